// Round 2
// baseline (399.275 us; speedup 1.0000x reference)
//
#include <hip/hip_runtime.h>
#include <math.h>

typedef unsigned short u16;
typedef __attribute__((ext_vector_type(8))) short s8v;
typedef __attribute__((ext_vector_type(4))) float f4v;

#define BH 16
#define SEQ 4096
#define DD 128

__device__ __forceinline__ float b2f(u16 h){ union{unsigned u; float f;} v; v.u=((unsigned)h)<<16; return v.f; }
__device__ __forceinline__ u16 f2b(float f){ union{float f; unsigned u;} v; v.f=f; unsigned r=v.u+0x7FFFu+((v.u>>16)&1u); return (u16)(r>>16); }
__device__ __forceinline__ f4v mm16(s8v a, s8v b, f4v c){ return __builtin_amdgcn_mfma_f32_16x16x32_bf16(a,b,c,0,0,0); }
__device__ __forceinline__ float dot4(float4 a, float4 b){ return a.x*b.x+a.y*b.y+a.z*b.z+a.w*b.w; }
// LDS-only barrier: p2's cross-wave traffic is LDS-only; global loads are
// lane-private, so no vmcnt drain needed -> prefetches stay in flight.
__device__ __forceinline__ void bar_lds(){
  asm volatile("s_waitcnt lgkmcnt(0)\n\ts_barrier" ::: "memory");
}

// ---------------------------------------------------------------------------
// Phase 1 (c=32) per chunk: T=(I-strictlower(kb kn^T))^-1, AL=trilincl(qn kn^T),
// w=T kb, u0=T vb, qen=AL w - qn, p=AL u0.  Also emits knT (bf16, [d][token]).
// ---------------------------------------------------------------------------
__global__ __launch_bounds__(512,4) void p1_kernel(
    const float* __restrict__ gq, const float* __restrict__ gk,
    const float* __restrict__ gv, const float* __restrict__ gbeta,
    u16* __restrict__ gw, u16* __restrict__ gqen, u16* __restrict__ gu0,
    u16* __restrict__ gknT, float* __restrict__ gik, float* __restrict__ gout)
{
  __shared__ u16 qnh[32][136], qnl[32][136];
  __shared__ u16 arena1[10240];
  __shared__ u16 vbT[128][40], kbT[128][40];
  __shared__ u16 arena2[8704];
  __shared__ float Amat[32][33];
  __shared__ float bet[32];

  u16 (*knh)[136] = (u16(*)[136])arena1;
  u16 (*knl)[136] = (u16(*)[136])(arena1+4352);
  u16 (*wTT)[40]  = (u16(*)[40])arena1;
  u16 (*u0T)[40]  = (u16(*)[40])(arena1+5120);
  u16 (*vb16)[136]= (u16(*)[136])arena2;
  u16 (*kb16)[136]= (u16(*)[136])(arena2+4352);
  u16 (*Tb)[40]   = (u16(*)[40])arena2;
  u16 (*ALb)[40]  = (u16(*)[40])(arena2+1280);

  const int cid = blockIdx.x, bh = cid>>7, ci = cid&127;
  const int t = threadIdx.x, wave = t>>6, lane = t&63, m = lane&15, qq = lane>>4;
  const size_t tokbase = (size_t)bh*SEQ + (size_t)ci*32;
  const size_t base = tokbase*DD;

  for (int p=0;p<2;++p){
    int idx = t + (p<<9);
    int r = idx>>5, c4 = (idx&31)<<2;
    float4 qv = *(const float4*)(gq + base + r*DD + c4);
    float4 kv = *(const float4*)(gk + base + r*DD + c4);
    float4 vv = *(const float4*)(gv + base + r*DD + c4);
    float nq = dot4(qv,qv), nk = dot4(kv,kv);
    nq += __shfl_xor(nq,1); nq += __shfl_xor(nq,2); nq += __shfl_xor(nq,4);
    nq += __shfl_xor(nq,8); nq += __shfl_xor(nq,16);
    nk += __shfl_xor(nk,1); nk += __shfl_xor(nk,2); nk += __shfl_xor(nk,4);
    nk += __shfl_xor(nk,8); nk += __shfl_xor(nk,16);
    float iq = 1.f/sqrtf(nq+1e-6f), ik = 1.f/sqrtf(nk+1e-6f);
    float bb = gbeta[tokbase + r];
    if ((idx&31)==0){ gik[tokbase+r]=ik; bet[r]=bb; }
    float qa[4]={qv.x,qv.y,qv.z,qv.w}, ka[4]={kv.x,kv.y,kv.z,kv.w}, va[4]={vv.x,vv.y,vv.z,vv.w};
    union{u16 s[4]; uint2 v;} hq,lq,hk,lk,sv,sb;
    #pragma unroll
    for(int i=0;i<4;++i){
      float qn = qa[i]*iq; u16 h1=f2b(qn); hq.s[i]=h1; lq.s[i]=f2b(qn-b2f(h1));
      float kn = ka[i]*ik; u16 h2=f2b(kn); hk.s[i]=h2; lk.s[i]=f2b(kn-b2f(h2));
      sv.s[i]=f2b(va[i]*bb); sb.s[i]=f2b(kn*bb);
    }
    *(uint2*)&qnh[r][c4]=hq.v; *(uint2*)&qnl[r][c4]=lq.v;
    *(uint2*)&knh[r][c4]=hk.v; *(uint2*)&knl[r][c4]=lk.v;
    *(uint2*)&vb16[r][c4]=sv.v; *(uint2*)&kb16[r][c4]=sb.v;
  }
  __syncthreads();

  {
    u16* kdst = gknT + ((size_t)(bh*32 + (ci>>2)))*16384 + (size_t)((ci&3)*32);
    for (int g=0; g<2; ++g){
      int tau = t + (g<<9);
      int r = tau & 31, d0 = (tau>>5)<<2;
      union{u16 s[4]; uint2 v;} vv, kk, kn4;
      vv.v  = *(uint2*)&vb16[r][d0];
      kk.v  = *(uint2*)&kb16[r][d0];
      kn4.v = *(uint2*)&knh[r][d0];
      #pragma unroll
      for(int i=0;i<4;++i){
        vbT[d0+i][r] = vv.s[i];
        kbT[d0+i][r] = kk.s[i];
        kdst[(size_t)(d0+i)*128 + r] = kn4.s[i];
      }
    }
  }
  __syncthreads();

  {
    const int TI[3]={0,1,1}, TJ[3]={0,0,1};
    if (wave < 3){
      int ti=TI[wave], tj=TJ[wave];
      f4v acc = {0.f,0.f,0.f,0.f};
      #pragma unroll
      for(int kc=0;kc<4;++kc){
        int ko = kc*32 + qq*8;
        s8v ah = *(const s8v*)&knh[ti*16+m][ko];
        s8v al = *(const s8v*)&knl[ti*16+m][ko];
        s8v bhv = *(const s8v*)&knh[tj*16+m][ko];
        s8v blv = *(const s8v*)&knl[tj*16+m][ko];
        acc = mm16(ah,bhv,acc); acc = mm16(ah,blv,acc); acc = mm16(al,bhv,acc);
      }
      #pragma unroll
      for(int r=0;r<4;++r){
        int row = ti*16+qq*4+r, col = tj*16+m;
        Amat[row][col] = (col<row)? (-bet[row]*acc[r]) : 0.f;
      }
    } else if (wave < 6){
      int ti=TI[wave-3], tj=TJ[wave-3];
      f4v acc = {0.f,0.f,0.f,0.f};
      #pragma unroll
      for(int kc=0;kc<4;++kc){
        int ko = kc*32 + qq*8;
        s8v ah = *(const s8v*)&qnh[ti*16+m][ko];
        s8v al = *(const s8v*)&qnl[ti*16+m][ko];
        s8v bhv = *(const s8v*)&knh[tj*16+m][ko];
        s8v blv = *(const s8v*)&knl[tj*16+m][ko];
        acc = mm16(ah,bhv,acc); acc = mm16(ah,blv,acc); acc = mm16(al,bhv,acc);
      }
      #pragma unroll
      for(int r=0;r<4;++r){
        int row = ti*16+qq*4+r, col = tj*16+m;
        ALb[row][col] = (col<=row)? f2b(acc[r]) : (u16)0;
      }
    } else if (wave == 6){
      #pragma unroll
      for(int r=0;r<4;++r) ALb[qq*4+r][16+m] = (u16)0;
    }
  }
  __syncthreads();

  if (t < 32){
    float a[32];
    #pragma unroll
    for(int i=0;i<32;++i) a[i] = (t<i)? Amat[i][t] : 0.f;
    #pragma unroll
    for(int i=2;i<32;++i){
      float s = a[i];
      #pragma unroll
      for(int j=1;j<i;++j) s += __shfl(a[i],j)*a[j];
      a[i] = s;
    }
    #pragma unroll
    for(int i=0;i<32;++i) Tb[i][t] = f2b(a[i] + (i==t?1.f:0.f));
  }
  __syncthreads();

  #pragma unroll
  for (int q8 = 0; q8 < 4; ++q8){
    int tau = wave + q8*8;
    bool isu = (tau < 16);
    int tile16 = tau & 15, rt = tile16>>3, dt = tile16&7;
    s8v aT = *(const s8v*)&Tb[rt*16+m][qq*8];
    s8v bB = isu ? *(const s8v*)&vbT[dt*16+m][qq*8] : *(const s8v*)&kbT[dt*16+m][qq*8];
    f4v acc = {0.f,0.f,0.f,0.f};
    acc = mm16(aT,bB,acc);
    int tok0 = rt*16 + qq*4, dcol = dt*16+m;
    u16* gdst = isu ? gu0 : gw;
    u16 (*ldst)[40] = isu ? u0T : wTT;
    union{u16 s[4]; uint2 v;} pk;
    #pragma unroll
    for(int r=0;r<4;++r){
      u16 hv = f2b(acc[r]); pk.s[r]=hv;
      gdst[(tokbase + tok0 + r)*DD + dcol] = hv;
    }
    *(uint2*)&ldst[dcol][tok0] = pk.v;
  }
  __syncthreads();

  #pragma unroll
  for (int q8 = 0; q8 < 4; ++q8){
    int tau = wave + q8*8;
    bool isq = (tau < 16);
    int tile16 = tau & 15, rt = tile16>>3, dt = tile16&7;
    s8v aA = *(const s8v*)&ALb[rt*16+m][qq*8];
    s8v bB = isq ? *(const s8v*)&wTT[dt*16+m][qq*8] : *(const s8v*)&u0T[dt*16+m][qq*8];
    f4v acc = {0.f,0.f,0.f,0.f};
    acc = mm16(aA,bB,acc);
    int tok0 = rt*16+qq*4, dcol = dt*16+m;
    #pragma unroll
    for(int r=0;r<4;++r){
      size_t gi = (tokbase+tok0+r)*DD + dcol;
      if (isq){
        float qn = b2f(qnh[tok0+r][dcol]) + b2f(qnl[tok0+r][dcol]);
        gqen[gi] = f2b(acc[r] - qn);
      } else {
        gout[gi] = acc[r];
      }
    }
  }
}

// ---------------------------------------------------------------------------
// merge<C>
// ---------------------------------------------------------------------------
template<int C>
__global__ __launch_bounds__(256) void merge_kernel(
    const float* __restrict__ gk, const float* __restrict__ gik,
    u16* __restrict__ gw, u16* __restrict__ gqen, u16* __restrict__ gu0,
    float* __restrict__ gout)
{
  constexpr int P = 2048 / C;
  constexpr int SM = C + 8;
  __shared__ u16 k1[C][136];
  __shared__ u16 w1T[128][SM], u01T[128][SM];
  __shared__ u16 Mw[C][SM], MG[C][SM];
  const int bh = blockIdx.x / P, pr = blockIdx.x % P;
  const int t = threadIdx.x, wave = t>>6, lane = t&63, m = lane&15, qq = lane>>4;
  const int base1 = pr*2*C, base2 = base1 + C;
  const size_t tb1 = (size_t)bh*SEQ + base1, tb2 = (size_t)bh*SEQ + base2;

  for(int p=0;p<C*32/256;++p){
    int idx = t + (p<<8); int j = idx>>5, c4 = (idx&31)<<2;
    float ik = gik[tb1 + j];
    float4 kv = *(const float4*)(gk + (tb1+j)*DD + c4);
    union{u16 s[4]; uint2 v;} pk;
    pk.s[0]=f2b(kv.x*ik); pk.s[1]=f2b(kv.y*ik); pk.s[2]=f2b(kv.z*ik); pk.s[3]=f2b(kv.w*ik);
    *(uint2*)&k1[j][c4] = pk.v;
  }
  for(int p=0;p<C*16/256;++p){
    int idx = t + (p<<8); int j = idx>>4, d8 = (idx&15)<<3;
    s8v wv = *(const s8v*)(gw + (tb1+j)*DD + d8);
    s8v uv = *(const s8v*)(gu0 + (tb1+j)*DD + d8);
    const u16* wsp = (const u16*)&wv; const u16* usp = (const u16*)&uv;
    for(int i=0;i<8;++i){ w1T[d8+i][j]=wsp[i]; u01T[d8+i][j]=usp[i]; }
  }
  __syncthreads();

  constexpr int NT = (C/16)*(C/16);
  for(int tile = wave; tile < NT; tile += 4){
    int ti = tile/(C/16), tj = tile%(C/16);
    f4v aw = {0.f,0.f,0.f,0.f}, ag = {0.f,0.f,0.f,0.f};
    for(int kc=0;kc<4;++kc){
      int ko = kc*32 + qq*8;
      s8v b  = *(const s8v*)&k1[tj*16+m][ko];
      s8v a1 = *(const s8v*)(gw   + (tb2 + ti*16+m)*DD + ko);
      s8v a2 = *(const s8v*)(gqen + (tb2 + ti*16+m)*DD + ko);
      aw = mm16(a1,b,aw); ag = mm16(a2,b,ag);
    }
    for(int r=0;r<4;++r){
      Mw[ti*16+qq*4+r][tj*16+m] = f2b(aw[r]);
      MG[ti*16+qq*4+r][tj*16+m] = f2b(ag[r]);
    }
  }
  __syncthreads();

  {
    const u16 (*Ma)[SM] = (wave==0||wave==2) ? Mw : MG;
    const u16 (*Bt)[SM] = (wave<2) ? w1T : u01T;
    for(int tile=0; tile<(C/16)*8; ++tile){
      int ti = tile>>3, dt = tile&7;
      f4v acc = {0.f,0.f,0.f,0.f};
      for(int kc=0;kc<C/32;++kc){
        int ko = kc*32+qq*8;
        s8v a = *(const s8v*)&Ma[ti*16+m][ko];
        s8v b = *(const s8v*)&Bt[dt*16+m][ko];
        acc = mm16(a,b,acc);
      }
      int d = dt*16+m;
      for(int r=0;r<4;++r){
        size_t gi = (tb2 + ti*16 + qq*4 + r)*DD + d;
        if (wave==0)      gw[gi]   = f2b(b2f(gw[gi])   - acc[r]);
        else if (wave==1) gqen[gi] = f2b(b2f(gqen[gi]) - acc[r]);
        else if (wave==2) gu0[gi]  = f2b(b2f(gu0[gi])  - acc[r]);
        else              gout[gi] = gout[gi] - acc[r];
      }
    }
  }
}

// ---------------------------------------------------------------------------
// Phase 2: scan over 32 chunks of 128.  u = u0 - w S; o = p - qen S; S += kn^T u.
// Round 2 restructure: the compiler was sinking the "prefetch" loads to their
// uses (VGPR_Count=80), serializing ~12 global-load latencies per scan step.
// Now: each operand group is reloaded for step ci+1 into the SAME registers
// immediately after its last use in step ci, and pinned with an empty
// asm volatile "+v" (non-rematerializable, ordered between the volatile
// barriers).  One overlapped latency per step instead of ~12 serial ones.
// ---------------------------------------------------------------------------
#define KEEP8(a,b,c,d,e,f,g,h) asm volatile("" : "+v"(a),"+v"(b),"+v"(c),"+v"(d),"+v"(e),"+v"(f),"+v"(g),"+v"(h))
#define KEEP4(a,b,c,d) asm volatile("" : "+v"(a),"+v"(b),"+v"(c),"+v"(d))

__global__ __launch_bounds__(512,2) void p2_kernel(
    const u16* __restrict__ gw, const u16* __restrict__ gqen,
    const u16* __restrict__ gu0, const u16* __restrict__ knT,
    float* __restrict__ gout)
{
  __shared__ u16 lSb[2][16][128];
  __shared__ u16 lub[2][16][128];
  const int bh = blockIdx.x & 15, slice = blockIdx.x >> 4;
  const int t = threadIdx.x, wave = t>>6, lane = t&63, m = lane&15, qq = lane>>4;
  f4v S = {0.f,0.f,0.f,0.f};
  float* out_o = gout;
  float* out_S = gout + (size_t)BH*SEQ*DD;
  const size_t bhb = (size_t)bh*SEQ;
  const int dv = slice*16 + m;
  const int swz = (m & 7) << 4;        // row-keyed 16B XOR swizzle
  char* rS0 = (char*)&lSb[0][m][0];
  char* rS1 = (char*)&lSb[1][m][0];
  char* rU0 = (char*)&lub[0][m][0];
  char* rU1 = (char*)&lub[1][m][0];

  const int row = wave*16 + m;
  const u16* wrow = gw   + (bhb + row)*DD + qq*8;
  const u16* qrow = gqen + (bhb + row)*DD + qq*8;
  const u16* krow = knT  + (size_t)bh*32*16384 + (size_t)row*DD + qq*8;
  const int j0 = wave*16 + qq*4;
  const size_t gi0 = (bhb + j0)*DD + dv;

  s8v wf[4], qf[4], kf[4];
  float u0f[4], pf[4];
  // prefetch step 0
  {
    #pragma unroll
    for(int kc=0;kc<4;++kc){
      wf[kc] = *(const s8v*)(wrow + kc*32);
      qf[kc] = *(const s8v*)(qrow + kc*32);
      kf[kc] = *(const s8v*)(krow + kc*32);
    }
    #pragma unroll
    for(int r=0;r<4;++r){
      u0f[r] = b2f(gu0[gi0 + (size_t)r*DD]);
      pf[r]  = out_o[gi0 + (size_t)r*DD];
    }
  }

  for (int ci = 0; ci < 32; ++ci) {
    const int cn = (ci + 1) & 31;                 // wraps harmlessly at the end
    const size_t nwo = (size_t)cn * (128*DD);     // next-step element offset (w/qen/u0/p)
    const size_t nko = (size_t)cn * 16384;        // next-step element offset (knT)
    const size_t cwo = (size_t)ci * (128*DD);

    // (a) S -> lSb (hi/lo), packed + swizzled
    {
      int bo = (j0*2) ^ swz;
      union{u16 s[4]; uint2 v;} ph, pl;
      #pragma unroll
      for(int r=0;r<4;++r){
        float v = S[r]; u16 hi = f2b(v); ph.s[r]=hi; pl.s[r]=f2b(v - b2f(hi));
      }
      *(uint2*)(rS0 + bo) = ph.v;
      *(uint2*)(rS1 + bo) = pl.v;
    }
    bar_lds();
    // (b) au = w.S, ao = qen.S  (hi/lo chains split: 4-deep each)
    f4v auh = {0.f,0.f,0.f,0.f}, aul = {0.f,0.f,0.f,0.f};
    f4v aoh = {0.f,0.f,0.f,0.f}, aol = {0.f,0.f,0.f,0.f};
    #pragma unroll
    for (int kc = 0; kc < 4; ++kc) {
      int bo = (kc*64 + qq*16) ^ swz;
      s8v bhv = *(const s8v*)(rS0 + bo);
      s8v blv = *(const s8v*)(rS1 + bo);
      auh = mm16(wf[kc],bhv,auh); aul = mm16(wf[kc],blv,aul);
      aoh = mm16(qf[kc],bhv,aoh); aol = mm16(qf[kc],blv,aol);
    }
    // wf/qf are dead now: reload for step ci+1 into the same registers, pin.
    #pragma unroll
    for(int kc=0;kc<4;++kc){
      wf[kc] = *(const s8v*)(wrow + nwo + kc*32);
      qf[kc] = *(const s8v*)(qrow + nwo + kc*32);
    }
    KEEP8(wf[0],wf[1],wf[2],wf[3],qf[0],qf[1],qf[2],qf[3]);
    // (c) u = u0 - au -> lub (hi/lo, packed+swizzled); o = p - ao -> global
    {
      int bo = (j0*2) ^ swz;
      union{u16 s[4]; uint2 v;} ph, pl;
      #pragma unroll
      for(int r=0;r<4;++r){
        float uv = u0f[r] - (auh[r] + aul[r]);
        u16 hi = f2b(uv); ph.s[r]=hi; pl.s[r]=f2b(uv - b2f(hi));
        out_o[gi0 + cwo + (size_t)r*DD] = pf[r] - (aoh[r] + aol[r]);
      }
      *(uint2*)(rU0 + bo) = ph.v;
      *(uint2*)(rU1 + bo) = pl.v;
    }
    // u0f/pf are dead now: reload for step ci+1, pin.
    #pragma unroll
    for(int r=0;r<4;++r){
      u0f[r] = b2f(gu0[gi0 + nwo + (size_t)r*DD]);
      pf[r]  = out_o[gi0 + nwo + (size_t)r*DD];
    }
    KEEP8(u0f[0],u0f[1],u0f[2],u0f[3],pf[0],pf[1],pf[2],pf[3]);
    bar_lds();
    // (d) S += kn^T u  (hi into S, lo into separate 4-deep chain, then add)
    f4v Sl = {0.f,0.f,0.f,0.f};
    #pragma unroll
    for (int jc = 0; jc < 4; ++jc) {
      int bo = (jc*64 + qq*16) ^ swz;
      s8v bhv = *(const s8v*)(rU0 + bo);
      s8v blv = *(const s8v*)(rU1 + bo);
      S  = mm16(kf[jc],bhv,S);
      Sl = mm16(kf[jc],blv,Sl);
    }
    S = S + Sl;
    // kf is dead now: reload for step ci+1, pin.
    #pragma unroll
    for(int kc=0;kc<4;++kc)
      kf[kc] = *(const s8v*)(krow + nko + kc*32);
    KEEP4(kf[0],kf[1],kf[2],kf[3]);
  }
  {
    int d0 = wave*16 + qq*4;
    #pragma unroll
    for(int r=0;r<4;++r)
      out_S[(size_t)bh*16384 + (size_t)(d0+r)*DD + dv] = S[r];
  }
}

extern "C" void kernel_launch(void* const* d_in, const int* in_sizes, int n_in,
                              void* d_out, int out_size, void* d_ws, size_t ws_size,
                              hipStream_t stream) {
  const float* q    = (const float*)d_in[0];
  const float* k    = (const float*)d_in[1];
  const float* v    = (const float*)d_in[2];
  const float* beta = (const float*)d_in[3];
  u16* wsu  = (u16*)d_ws;
  u16* gw   = wsu;
  u16* gqen = wsu + 8388608;
  u16* gu0  = wsu + 16777216;
  u16* knT  = wsu + 25165824;
  float* gik = (float*)(wsu + 33554432);
  float* out = (float*)d_out;

  p1_kernel<<<dim3(2048), dim3(512), 0, stream>>>(q, k, v, beta, gw, gqen, gu0, knT, gik, out);
  merge_kernel<32><<<dim3(1024), dim3(256), 0, stream>>>(k, gik, gw, gqen, gu0, out);
  merge_kernel<64><<<dim3(512),  dim3(256), 0, stream>>>(k, gik, gw, gqen, gu0, out);
  p2_kernel<<<dim3(128), dim3(512), 0, stream>>>(gw, gqen, gu0, knT, out);
}

// Round 3
// 393.799 us; speedup vs baseline: 1.0139x; 1.0139x over previous
//
#include <hip/hip_runtime.h>
#include <math.h>

typedef unsigned short u16;
typedef __attribute__((ext_vector_type(8))) short s8v;
typedef __attribute__((ext_vector_type(4))) float f4v;

#define BH 16
#define SEQ 4096
#define DD 128

__device__ __forceinline__ float b2f(u16 h){ union{unsigned u; float f;} v; v.u=((unsigned)h)<<16; return v.f; }
__device__ __forceinline__ u16 f2b(float f){ union{float f; unsigned u;} v; v.f=f; unsigned r=v.u+0x7FFFu+((v.u>>16)&1u); return (u16)(r>>16); }
__device__ __forceinline__ f4v mm16(s8v a, s8v b, f4v c){ return __builtin_amdgcn_mfma_f32_16x16x32_bf16(a,b,c,0,0,0); }
__device__ __forceinline__ float dot4(float4 a, float4 b){ return a.x*b.x+a.y*b.y+a.z*b.z+a.w*b.w; }
// LDS-only barrier: cross-wave traffic is LDS-only; no vmcnt drain here so
// global_load_lds staging stays in flight across the barrier (m201 pattern).
__device__ __forceinline__ void bar_lds(){
  asm volatile("s_waitcnt lgkmcnt(0)\n\ts_barrier" ::: "memory");
}
#define FENCE() asm volatile("" ::: "memory")

// Direct global->LDS DMA, 16B per lane, zero VGPR destinations.
// LDS dest = wave-uniform base + lane*16; global src is per-lane.
typedef __attribute__((address_space(1))) void gas_t;
typedef __attribute__((address_space(3))) void las_t;
__device__ __forceinline__ void gl16(const u16* g, const u16* l){
  __builtin_amdgcn_global_load_lds(
      (gas_t*)(unsigned long long)(const void*)g,
      (las_t*)(unsigned)(unsigned long long)(const void*)l,
      16, 0, 0);
}

// ---------------------------------------------------------------------------
// Phase 1 (c=32) per chunk: T=(I-strictlower(kb kn^T))^-1, AL=trilincl(qn kn^T),
// w=T kb, u0=T vb, qen=AL w - qn, p=AL u0.  Also emits knT (bf16, [d][token]).
// ---------------------------------------------------------------------------
__global__ __launch_bounds__(512,4) void p1_kernel(
    const float* __restrict__ gq, const float* __restrict__ gk,
    const float* __restrict__ gv, const float* __restrict__ gbeta,
    u16* __restrict__ gw, u16* __restrict__ gqen, u16* __restrict__ gu0,
    u16* __restrict__ gknT, float* __restrict__ gik, float* __restrict__ gout)
{
  __shared__ u16 qnh[32][136], qnl[32][136];
  __shared__ u16 arena1[10240];
  __shared__ u16 vbT[128][40], kbT[128][40];
  __shared__ u16 arena2[8704];
  __shared__ float Amat[32][33];
  __shared__ float bet[32];

  u16 (*knh)[136] = (u16(*)[136])arena1;
  u16 (*knl)[136] = (u16(*)[136])(arena1+4352);
  u16 (*wTT)[40]  = (u16(*)[40])arena1;
  u16 (*u0T)[40]  = (u16(*)[40])(arena1+5120);
  u16 (*vb16)[136]= (u16(*)[136])arena2;
  u16 (*kb16)[136]= (u16(*)[136])(arena2+4352);
  u16 (*Tb)[40]   = (u16(*)[40])arena2;
  u16 (*ALb)[40]  = (u16(*)[40])(arena2+1280);

  const int cid = blockIdx.x, bh = cid>>7, ci = cid&127;
  const int t = threadIdx.x, wave = t>>6, lane = t&63, m = lane&15, qq = lane>>4;
  const size_t tokbase = (size_t)bh*SEQ + (size_t)ci*32;
  const size_t base = tokbase*DD;

  for (int p=0;p<2;++p){
    int idx = t + (p<<9);
    int r = idx>>5, c4 = (idx&31)<<2;
    float4 qv = *(const float4*)(gq + base + r*DD + c4);
    float4 kv = *(const float4*)(gk + base + r*DD + c4);
    float4 vv = *(const float4*)(gv + base + r*DD + c4);
    float nq = dot4(qv,qv), nk = dot4(kv,kv);
    nq += __shfl_xor(nq,1); nq += __shfl_xor(nq,2); nq += __shfl_xor(nq,4);
    nq += __shfl_xor(nq,8); nq += __shfl_xor(nq,16);
    nk += __shfl_xor(nk,1); nk += __shfl_xor(nk,2); nk += __shfl_xor(nk,4);
    nk += __shfl_xor(nk,8); nk += __shfl_xor(nk,16);
    float iq = 1.f/sqrtf(nq+1e-6f), ik = 1.f/sqrtf(nk+1e-6f);
    float bb = gbeta[tokbase + r];
    if ((idx&31)==0){ gik[tokbase+r]=ik; bet[r]=bb; }
    float qa[4]={qv.x,qv.y,qv.z,qv.w}, ka[4]={kv.x,kv.y,kv.z,kv.w}, va[4]={vv.x,vv.y,vv.z,vv.w};
    union{u16 s[4]; uint2 v;} hq,lq,hk,lk,sv,sb;
    #pragma unroll
    for(int i=0;i<4;++i){
      float qn = qa[i]*iq; u16 h1=f2b(qn); hq.s[i]=h1; lq.s[i]=f2b(qn-b2f(h1));
      float kn = ka[i]*ik; u16 h2=f2b(kn); hk.s[i]=h2; lk.s[i]=f2b(kn-b2f(h2));
      sv.s[i]=f2b(va[i]*bb); sb.s[i]=f2b(kn*bb);
    }
    *(uint2*)&qnh[r][c4]=hq.v; *(uint2*)&qnl[r][c4]=lq.v;
    *(uint2*)&knh[r][c4]=hk.v; *(uint2*)&knl[r][c4]=lk.v;
    *(uint2*)&vb16[r][c4]=sv.v; *(uint2*)&kb16[r][c4]=sb.v;
  }
  __syncthreads();

  {
    u16* kdst = gknT + ((size_t)(bh*32 + (ci>>2)))*16384 + (size_t)((ci&3)*32);
    for (int g=0; g<2; ++g){
      int tau = t + (g<<9);
      int r = tau & 31, d0 = (tau>>5)<<2;
      union{u16 s[4]; uint2 v;} vv, kk, kn4;
      vv.v  = *(uint2*)&vb16[r][d0];
      kk.v  = *(uint2*)&kb16[r][d0];
      kn4.v = *(uint2*)&knh[r][d0];
      #pragma unroll
      for(int i=0;i<4;++i){
        vbT[d0+i][r] = vv.s[i];
        kbT[d0+i][r] = kk.s[i];
        kdst[(size_t)(d0+i)*128 + r] = kn4.s[i];
      }
    }
  }
  __syncthreads();

  {
    const int TI[3]={0,1,1}, TJ[3]={0,0,1};
    if (wave < 3){
      int ti=TI[wave], tj=TJ[wave];
      f4v acc = {0.f,0.f,0.f,0.f};
      #pragma unroll
      for(int kc=0;kc<4;++kc){
        int ko = kc*32 + qq*8;
        s8v ah = *(const s8v*)&knh[ti*16+m][ko];
        s8v al = *(const s8v*)&knl[ti*16+m][ko];
        s8v bhv = *(const s8v*)&knh[tj*16+m][ko];
        s8v blv = *(const s8v*)&knl[tj*16+m][ko];
        acc = mm16(ah,bhv,acc); acc = mm16(ah,blv,acc); acc = mm16(al,bhv,acc);
      }
      #pragma unroll
      for(int r=0;r<4;++r){
        int row = ti*16+qq*4+r, col = tj*16+m;
        Amat[row][col] = (col<row)? (-bet[row]*acc[r]) : 0.f;
      }
    } else if (wave < 6){
      int ti=TI[wave-3], tj=TJ[wave-3];
      f4v acc = {0.f,0.f,0.f,0.f};
      #pragma unroll
      for(int kc=0;kc<4;++kc){
        int ko = kc*32 + qq*8;
        s8v ah = *(const s8v*)&qnh[ti*16+m][ko];
        s8v al = *(const s8v*)&qnl[ti*16+m][ko];
        s8v bhv = *(const s8v*)&knh[tj*16+m][ko];
        s8v blv = *(const s8v*)&knl[tj*16+m][ko];
        acc = mm16(ah,bhv,acc); acc = mm16(ah,blv,acc); acc = mm16(al,bhv,acc);
      }
      #pragma unroll
      for(int r=0;r<4;++r){
        int row = ti*16+qq*4+r, col = tj*16+m;
        ALb[row][col] = (col<=row)? f2b(acc[r]) : (u16)0;
      }
    } else if (wave == 6){
      #pragma unroll
      for(int r=0;r<4;++r) ALb[qq*4+r][16+m] = (u16)0;
    }
  }
  __syncthreads();

  if (t < 32){
    float a[32];
    #pragma unroll
    for(int i=0;i<32;++i) a[i] = (t<i)? Amat[i][t] : 0.f;
    #pragma unroll
    for(int i=2;i<32;++i){
      float s = a[i];
      #pragma unroll
      for(int j=1;j<i;++j) s += __shfl(a[i],j)*a[j];
      a[i] = s;
    }
    #pragma unroll
    for(int i=0;i<32;++i) Tb[i][t] = f2b(a[i] + (i==t?1.f:0.f));
  }
  __syncthreads();

  #pragma unroll
  for (int q8 = 0; q8 < 4; ++q8){
    int tau = wave + q8*8;
    bool isu = (tau < 16);
    int tile16 = tau & 15, rt = tile16>>3, dt = tile16&7;
    s8v aT = *(const s8v*)&Tb[rt*16+m][qq*8];
    s8v bB = isu ? *(const s8v*)&vbT[dt*16+m][qq*8] : *(const s8v*)&kbT[dt*16+m][qq*8];
    f4v acc = {0.f,0.f,0.f,0.f};
    acc = mm16(aT,bB,acc);
    int tok0 = rt*16 + qq*4, dcol = dt*16+m;
    u16* gdst = isu ? gu0 : gw;
    u16 (*ldst)[40] = isu ? u0T : wTT;
    union{u16 s[4]; uint2 v;} pk;
    #pragma unroll
    for(int r=0;r<4;++r){
      u16 hv = f2b(acc[r]); pk.s[r]=hv;
      gdst[(tokbase + tok0 + r)*DD + dcol] = hv;
    }
    *(uint2*)&ldst[dcol][tok0] = pk.v;
  }
  __syncthreads();

  #pragma unroll
  for (int q8 = 0; q8 < 4; ++q8){
    int tau = wave + q8*8;
    bool isq = (tau < 16);
    int tile16 = tau & 15, rt = tile16>>3, dt = tile16&7;
    s8v aA = *(const s8v*)&ALb[rt*16+m][qq*8];
    s8v bB = isq ? *(const s8v*)&wTT[dt*16+m][qq*8] : *(const s8v*)&u0T[dt*16+m][qq*8];
    f4v acc = {0.f,0.f,0.f,0.f};
    acc = mm16(aA,bB,acc);
    int tok0 = rt*16+qq*4, dcol = dt*16+m;
    #pragma unroll
    for(int r=0;r<4;++r){
      size_t gi = (tokbase+tok0+r)*DD + dcol;
      if (isq){
        float qn = b2f(qnh[tok0+r][dcol]) + b2f(qnl[tok0+r][dcol]);
        gqen[gi] = f2b(acc[r] - qn);
      } else {
        gout[gi] = acc[r];
      }
    }
  }
}

// ---------------------------------------------------------------------------
// merge<C>
// ---------------------------------------------------------------------------
template<int C>
__global__ __launch_bounds__(256) void merge_kernel(
    const float* __restrict__ gk, const float* __restrict__ gik,
    u16* __restrict__ gw, u16* __restrict__ gqen, u16* __restrict__ gu0,
    float* __restrict__ gout)
{
  constexpr int P = 2048 / C;
  constexpr int SM = C + 8;
  __shared__ u16 k1[C][136];
  __shared__ u16 w1T[128][SM], u01T[128][SM];
  __shared__ u16 Mw[C][SM], MG[C][SM];
  const int bh = blockIdx.x / P, pr = blockIdx.x % P;
  const int t = threadIdx.x, wave = t>>6, lane = t&63, m = lane&15, qq = lane>>4;
  const int base1 = pr*2*C, base2 = base1 + C;
  const size_t tb1 = (size_t)bh*SEQ + base1, tb2 = (size_t)bh*SEQ + base2;

  for(int p=0;p<C*32/256;++p){
    int idx = t + (p<<8); int j = idx>>5, c4 = (idx&31)<<2;
    float ik = gik[tb1 + j];
    float4 kv = *(const float4*)(gk + (tb1+j)*DD + c4);
    union{u16 s[4]; uint2 v;} pk;
    pk.s[0]=f2b(kv.x*ik); pk.s[1]=f2b(kv.y*ik); pk.s[2]=f2b(kv.z*ik); pk.s[3]=f2b(kv.w*ik);
    *(uint2*)&k1[j][c4] = pk.v;
  }
  for(int p=0;p<C*16/256;++p){
    int idx = t + (p<<8); int j = idx>>4, d8 = (idx&15)<<3;
    s8v wv = *(const s8v*)(gw + (tb1+j)*DD + d8);
    s8v uv = *(const s8v*)(gu0 + (tb1+j)*DD + d8);
    const u16* wsp = (const u16*)&wv; const u16* usp = (const u16*)&uv;
    for(int i=0;i<8;++i){ w1T[d8+i][j]=wsp[i]; u01T[d8+i][j]=usp[i]; }
  }
  __syncthreads();

  constexpr int NT = (C/16)*(C/16);
  for(int tile = wave; tile < NT; tile += 4){
    int ti = tile/(C/16), tj = tile%(C/16);
    f4v aw = {0.f,0.f,0.f,0.f}, ag = {0.f,0.f,0.f,0.f};
    for(int kc=0;kc<4;++kc){
      int ko = kc*32 + qq*8;
      s8v b  = *(const s8v*)&k1[tj*16+m][ko];
      s8v a1 = *(const s8v*)(gw   + (tb2 + ti*16+m)*DD + ko);
      s8v a2 = *(const s8v*)(gqen + (tb2 + ti*16+m)*DD + ko);
      aw = mm16(a1,b,aw); ag = mm16(a2,b,ag);
    }
    for(int r=0;r<4;++r){
      Mw[ti*16+qq*4+r][tj*16+m] = f2b(aw[r]);
      MG[ti*16+qq*4+r][tj*16+m] = f2b(ag[r]);
    }
  }
  __syncthreads();

  {
    const u16 (*Ma)[SM] = (wave==0||wave==2) ? Mw : MG;
    const u16 (*Bt)[SM] = (wave<2) ? w1T : u01T;
    for(int tile=0; tile<(C/16)*8; ++tile){
      int ti = tile>>3, dt = tile&7;
      f4v acc = {0.f,0.f,0.f,0.f};
      for(int kc=0;kc<C/32;++kc){
        int ko = kc*32+qq*8;
        s8v a = *(const s8v*)&Ma[ti*16+m][ko];
        s8v b = *(const s8v*)&Bt[dt*16+m][ko];
        acc = mm16(a,b,acc);
      }
      int d = dt*16+m;
      for(int r=0;r<4;++r){
        size_t gi = (tb2 + ti*16 + qq*4 + r)*DD + d;
        if (wave==0)      gw[gi]   = f2b(b2f(gw[gi])   - acc[r]);
        else if (wave==1) gqen[gi] = f2b(b2f(gqen[gi]) - acc[r]);
        else if (wave==2) gu0[gi]  = f2b(b2f(gu0[gi])  - acc[r]);
        else              gout[gi] = gout[gi] - acc[r];
      }
    }
  }
}

// ---------------------------------------------------------------------------
// Phase 2: scan over 32 chunks of 128.  u = u0 - w S; o = p - qen S; S += kn^T u.
// Round 3: w/qen/kn operands staged via global_load_lds (zero VGPR in flight;
// the register allocator can no longer serialize the loads).  Staging is
// wave-private (each wave reads back exactly the lanes it staged), so no
// barrier publication is needed; a single counted s_waitcnt vmcnt(8) per step
// (one phase after issue) retires the 12 staging DMAs while leaving the 8
// u0/p register loads in flight.  kn ping-pong (consumed one step after
// staging).  Dynamic LDS 144KB: lSb 8K | lub 8K | W 32K | Q 32K | K 2x32K.
// ---------------------------------------------------------------------------
__global__ __launch_bounds__(512,2) void p2_kernel(
    const u16* __restrict__ gw, const u16* __restrict__ gqen,
    const u16* __restrict__ gu0, const u16* __restrict__ knT,
    float* __restrict__ gout)
{
  extern __shared__ u16 smem[];   // 73728 u16 = 147456 B
  // u16 offsets:
  //   lSb[2][16][128] @ 0      lub[2][16][128] @ 4096
  //   W[8][4][64][8]  @ 8192   Q @ 24576       K[2][8][4][64][8] @ 40960
  const int bh = blockIdx.x & 15, slice = blockIdx.x >> 4;
  const int t = threadIdx.x, wave = t>>6, lane = t&63, m = lane&15, qq = lane>>4;
  f4v S = {0.f,0.f,0.f,0.f};
  float* out_o = gout;
  float* out_S = gout + (size_t)BH*SEQ*DD;
  const size_t bhb = (size_t)bh*SEQ;
  const int dv = slice*16 + m;
  const int swz = (m & 7) << 4;        // row-keyed 16B XOR swizzle
  char* smc = (char*)smem;
  char* rS0 = smc + m*256;             // lSb[0][m]
  char* rS1 = smc + 4096*2 - 4096 + 4096 + m*256 - 4096 + 0;  // placeholder fix below
  rS1 = smc + 4096 + m*256;            // lSb[1][m]  (lSb[1] @ u16 2048 = byte 4096)
  char* rU0 = smc + 8192 + m*256;      // lub[0][m]  (u16 4096)
  char* rU1 = smc + 12288 + m*256;     // lub[1][m]  (u16 6144)
  u16* Wl = smem + 8192  + wave*2048;  // this wave's W staging (4 kc * 512)
  u16* Ql = smem + 24576 + wave*2048;
  u16* Kl = smem + 40960 + wave*2048;  // + parity*16384

  const int row = wave*16 + m;
  const u16* wsrc = gw   + (bhb + row)*DD + qq*8;
  const u16* qsrc = gqen + (bhb + row)*DD + qq*8;
  const u16* ksrc = knT  + (size_t)bh*32*16384 + (size_t)row*DD + qq*8;
  const int j0 = wave*16 + qq*4;
  const size_t gi0 = (bhb + j0)*DD + dv;

  float u0f[4], pf[4];
  // prologue: stage step 0 into W/Q/K[0]; load u0/p for step 0.
  {
    #pragma unroll
    for(int kc=0;kc<4;++kc){
      gl16(wsrc + kc*32, Wl + kc*512);
      gl16(qsrc + kc*32, Ql + kc*512);
      gl16(ksrc + kc*32, Kl + kc*512);
    }
    #pragma unroll
    for(int r=0;r<4;++r){
      u0f[r] = b2f(gu0[gi0 + (size_t)r*DD]);
      pf[r]  = out_o[gi0 + (size_t)r*DD];
    }
  }

  for (int ci = 0; ci < 32; ++ci) {
    const int cn = (ci + 1) & 31;                 // wraps harmlessly at the end
    const size_t nwo = (size_t)cn * (128*DD);
    const size_t nko = (size_t)cn * 16384;
    const size_t cwo = (size_t)ci * (128*DD);

    // (a) S -> lSb (hi/lo), packed + swizzled
    {
      int bo = (j0*2) ^ swz;
      union{u16 s[4]; uint2 v;} ph, pl;
      #pragma unroll
      for(int r=0;r<4;++r){
        float v = S[r]; u16 hi = f2b(v); ph.s[r]=hi; pl.s[r]=f2b(v - b2f(hi));
      }
      *(uint2*)(rS0 + bo) = ph.v;
      *(uint2*)(rS1 + bo) = pl.v;
    }
    bar_lds();
    // retire last step's 12 staging DMAs (issued ~2/3 step ago); keep the
    // 8 newest VMEM ops (u0/p reloads) in flight.
    asm volatile("s_waitcnt vmcnt(8)" ::: "memory");
    // (b) au = w.S, ao = qen.S  (hi/lo chains split: 4-deep each)
    f4v auh = {0.f,0.f,0.f,0.f}, aul = {0.f,0.f,0.f,0.f};
    f4v aoh = {0.f,0.f,0.f,0.f}, aol = {0.f,0.f,0.f,0.f};
    #pragma unroll
    for (int kc = 0; kc < 4; ++kc) {
      int bo = (kc*64 + qq*16) ^ swz;
      s8v wfr = *(const s8v*)(Wl + kc*512 + lane*8);
      s8v qfr = *(const s8v*)(Ql + kc*512 + lane*8);
      s8v bhv = *(const s8v*)(rS0 + bo);
      s8v blv = *(const s8v*)(rS1 + bo);
      auh = mm16(wfr,bhv,auh); aul = mm16(wfr,blv,aul);
      aoh = mm16(qfr,bhv,aoh); aol = mm16(qfr,blv,aol);
    }
    FENCE();
    // stage step ci+1: 12 global_load_lds, zero VGPR destinations.
    {
      u16* Kp = Kl + (cn&1)*16384;
      #pragma unroll
      for(int kc=0;kc<4;++kc){
        gl16(wsrc + nwo + kc*32, Wl + kc*512);
        gl16(qsrc + nwo + kc*32, Ql + kc*512);
        gl16(ksrc + nko + kc*32, Kp + kc*512);
      }
    }
    FENCE();
    // (c) u = u0 - au -> lub (hi/lo, packed+swizzled); o = p - ao -> global;
    //     then reload u0/p for step ci+1 (plain register loads, 8 VMEM).
    {
      int bo = (j0*2) ^ swz;
      union{u16 s[4]; uint2 v;} ph, pl;
      #pragma unroll
      for(int r=0;r<4;++r){
        float uv = u0f[r] - (auh[r] + aul[r]);
        u16 hi = f2b(uv); ph.s[r]=hi; pl.s[r]=f2b(uv - b2f(hi));
        out_o[gi0 + cwo + (size_t)r*DD] = pf[r] - (aoh[r] + aol[r]);
      }
      *(uint2*)(rU0 + bo) = ph.v;
      *(uint2*)(rU1 + bo) = pl.v;
      #pragma unroll
      for(int r=0;r<4;++r){
        u0f[r] = b2f(gu0[gi0 + nwo + (size_t)r*DD]);
        pf[r]  = out_o[gi0 + nwo + (size_t)r*DD];
      }
    }
    bar_lds();
    // (d) S += kn^T u  (hi into S, lo into separate 4-deep chain, then add)
    f4v Sl = {0.f,0.f,0.f,0.f};
    {
      const u16* Kc = Kl + (ci&1)*16384;
      #pragma unroll
      for (int jc = 0; jc < 4; ++jc) {
        int bo = (jc*64 + qq*16) ^ swz;
        s8v kfr = *(const s8v*)(Kc + jc*512 + lane*8);
        s8v bhv = *(const s8v*)(rU0 + bo);
        s8v blv = *(const s8v*)(rU1 + bo);
        S  = mm16(kfr,bhv,S);
        Sl = mm16(kfr,blv,Sl);
      }
    }
    S = S + Sl;
  }
  {
    int d0 = wave*16 + qq*4;
    #pragma unroll
    for(int r=0;r<4;++r)
      out_S[(size_t)bh*16384 + (size_t)(d0+r)*DD + dv] = S[r];
  }
}

extern "C" void kernel_launch(void* const* d_in, const int* in_sizes, int n_in,
                              void* d_out, int out_size, void* d_ws, size_t ws_size,
                              hipStream_t stream) {
  const float* q    = (const float*)d_in[0];
  const float* k    = (const float*)d_in[1];
  const float* v    = (const float*)d_in[2];
  const float* beta = (const float*)d_in[3];
  u16* wsu  = (u16*)d_ws;
  u16* gw   = wsu;
  u16* gqen = wsu + 8388608;
  u16* gu0  = wsu + 16777216;
  u16* knT  = wsu + 25165824;
  float* gik = (float*)(wsu + 33554432);
  float* out = (float*)d_out;

  static bool attr_done = false;
  if (!attr_done){
    hipFuncSetAttribute((const void*)p2_kernel,
                        hipFuncAttributeMaxDynamicSharedMemorySize, 147456);
    attr_done = true;
  }

  p1_kernel<<<dim3(2048), dim3(512), 0, stream>>>(q, k, v, beta, gw, gqen, gu0, knT, gik, out);
  merge_kernel<32><<<dim3(1024), dim3(256), 0, stream>>>(k, gik, gw, gqen, gu0, out);
  merge_kernel<64><<<dim3(512),  dim3(256), 0, stream>>>(k, gik, gw, gqen, gu0, out);
  p2_kernel<<<dim3(128), dim3(512), 147456, stream>>>(gw, gqen, gu0, knT, out);
}